// Round 2
// baseline (353.719 us; speedup 1.0000x reference)
//
#include <hip/hip_runtime.h>
#include <hip/hip_bf16.h>

#define K_CODES 512
#define CDIM    256
#define HW      1024
#define NBATCH  64
#define SZ      260   // padded LDS row stride (floats)

// ---------------- Kernel 0: codebook squared norms ----------------
__global__ __launch_bounds__(64) void vq_enorm(const float* __restrict__ cb,
                                               float* __restrict__ enorm) {
    int k = blockIdx.x;
    int l = threadIdx.x;  // 0..63
    float4 v = *reinterpret_cast<const float4*>(cb + (size_t)k * CDIM + l * 4);
    float s = (v.x * v.x + v.y * v.y) + (v.z * v.z + v.w * v.w);
#pragma unroll
    for (int off = 1; off < 64; off <<= 1) s += __shfl_xor(s, off, 64);
    if (l == 0) enorm[k] = s;
}

// ---------------- Kernel 1: distances + argmin ----------------
// Block: 64 rows (one (b, n0..n0+63) slab), 512 threads.
// Per-thread register tile: 4 rows x 2 codes, K looped in float4 chunks.
__global__ __launch_bounds__(512) void vq_argmin(const float* __restrict__ z,
                                                 const float* __restrict__ cb,
                                                 const float* __restrict__ enorm,
                                                 int* __restrict__ out_idx) {
    __shared__ float zs[64][SZ];
    __shared__ float es[64][SZ];
    __shared__ float ens[K_CODES];
    __shared__ float zn[64];
    __shared__ float red_d[64][32];
    __shared__ int   red_i[64][32];

    const int t  = threadIdx.x;
    const int r0 = blockIdx.x * 64;      // global row base (row = b*HW + n)
    const int b  = r0 >> 10;             // 64 rows never straddle a batch
    const int n0 = r0 & 1023;
    const float* zb = z + (size_t)b * CDIM * HW;

    // Stage z-tile: zs[i][c] = z[b][c][n0+i]  (transpose on the fly)
#pragma unroll
    for (int p = 0; p < 8; ++p) {
        int lin = p * 512 + t;
        int c   = lin >> 4;            // 0..255
        int i0  = (lin & 15) << 2;     // 0..60
        float4 v = *reinterpret_cast<const float4*>(zb + (size_t)c * HW + n0 + i0);
        zs[i0 + 0][c] = v.x;
        zs[i0 + 1][c] = v.y;
        zs[i0 + 2][c] = v.z;
        zs[i0 + 3][c] = v.w;
    }
    if (t < K_CODES) ens[t] = enorm[t];
    __syncthreads();

    // Row squared norms (threads 0..63)
    if (t < 64) {
        float s0 = 0.f, s1 = 0.f, s2 = 0.f, s3 = 0.f;
        for (int c = 0; c < CDIM; c += 4) {
            float4 v = *reinterpret_cast<const float4*>(&zs[t][c]);
            s0 += v.x * v.x; s1 += v.y * v.y; s2 += v.z * v.z; s3 += v.w * v.w;
        }
        zn[t] = (s0 + s1) + (s2 + s3);
    }

    const int ty   = t >> 5;     // 0..15
    const int tx   = t & 31;     // 0..31
    const int row0 = ty * 4;

    float best_d[4];
    int   best_i[4];
#pragma unroll
    for (int i = 0; i < 4; ++i) { best_d[i] = 3.4e38f; best_i[i] = 0; }

    for (int K0 = 0; K0 < K_CODES; K0 += 64) {
        __syncthreads();  // prev tile's es reads done; also covers zn/ens for tile 0
        // Stage code tile: es[j][c] = cb[K0+j][c]
#pragma unroll
        for (int p = 0; p < 8; ++p) {
            int lin = p * 512 + t;
            int j   = lin >> 6;           // 0..63
            int c4  = (lin & 63) << 2;    // 0..252
            *reinterpret_cast<float4*>(&es[j][c4]) =
                *reinterpret_cast<const float4*>(cb + (size_t)(K0 + j) * CDIM + c4);
        }
        __syncthreads();

        float acc[4][2];
#pragma unroll
        for (int i = 0; i < 4; ++i) { acc[i][0] = 0.f; acc[i][1] = 0.f; }

#pragma unroll 4
        for (int k = 0; k < CDIM; k += 4) {
            float4 a0 = *reinterpret_cast<const float4*>(&zs[row0 + 0][k]);
            float4 a1 = *reinterpret_cast<const float4*>(&zs[row0 + 1][k]);
            float4 a2 = *reinterpret_cast<const float4*>(&zs[row0 + 2][k]);
            float4 a3 = *reinterpret_cast<const float4*>(&zs[row0 + 3][k]);
            float4 e0 = *reinterpret_cast<const float4*>(&es[tx][k]);
            float4 e1 = *reinterpret_cast<const float4*>(&es[tx + 32][k]);
            float4 aa[4] = {a0, a1, a2, a3};
#pragma unroll
            for (int i = 0; i < 4; ++i) {
#pragma unroll
                for (int j = 0; j < 2; ++j) {
                    float4 e = j ? e1 : e0;
                    acc[i][j] += aa[i].x * e.x;
                    acc[i][j] += aa[i].y * e.y;
                    acc[i][j] += aa[i].z * e.z;
                    acc[i][j] += aa[i].w * e.w;
                }
            }
        }

        // dist = (zn - 2*dot) + en  -- replicate numpy's fp32 rounding
#pragma unroll
        for (int i = 0; i < 4; ++i) {
            float zni = zn[row0 + i];
#pragma unroll
            for (int j = 0; j < 2; ++j) {
                int code = K0 + j * 32 + tx;   // ascending visit order per thread
                float d = (zni - 2.0f * acc[i][j]) + ens[code];
                if (d < best_d[i]) { best_d[i] = d; best_i[i] = code; }
            }
        }
    }

    __syncthreads();
#pragma unroll
    for (int i = 0; i < 4; ++i) {
        red_d[row0 + i][tx] = best_d[i];
        red_i[row0 + i][tx] = best_i[i];
    }
    __syncthreads();
    if (t < 64) {
        float bd = red_d[t][0];
        int   bi = red_i[t][0];
        for (int x = 1; x < 32; ++x) {
            float d = red_d[t][x];
            int   ii = red_i[t][x];
            if (d < bd || (d == bd && ii < bi)) { bd = d; bi = ii; }
        }
        out_idx[r0 + t] = bi;
    }
}

// ---------------- Kernel 2: gather + transpose write + index write ----------------
// Block: (b, n0) slab of 64 n-positions; 256 threads; float32 output.
__global__ __launch_bounds__(256) void vq_gather(const float* __restrict__ cb,
                                                 const int* __restrict__ idx,
                                                 float* __restrict__ out) {
    const int blk = blockIdx.x;
    const int b   = blk >> 4;
    const int n0  = (blk & 15) << 6;
    const int t   = threadIdx.x;
    const int n   = t & 63;
    const int c0  = t >> 6;   // 0..3
    const int code = idx[b * HW + n0 + n];
    const float* crow = cb + (size_t)code * CDIM;
    float* ob = out + (size_t)b * CDIM * HW + n0 + n;

    if (c0 == 0) {
        // index output region starts after z_q (16,777,216 float elements)
        out[(size_t)NBATCH * CDIM * HW + (size_t)b * HW + n0 + n] = (float)code;
    }

#pragma unroll 4
    for (int q = 0; q < 64; q += 4) {
        int c = c0 * 64 + q;
        float4 v = *reinterpret_cast<const float4*>(crow + c);
        ob[(size_t)(c + 0) * HW] = v.x;
        ob[(size_t)(c + 1) * HW] = v.y;
        ob[(size_t)(c + 2) * HW] = v.z;
        ob[(size_t)(c + 3) * HW] = v.w;
    }
}

extern "C" void kernel_launch(void* const* d_in, const int* in_sizes, int n_in,
                              void* d_out, int out_size, void* d_ws, size_t ws_size,
                              hipStream_t stream) {
    const float* z  = (const float*)d_in[0];
    const float* cb = (const float*)d_in[1];
    float* out = (float*)d_out;

    int*   idx   = (int*)d_ws;                                    // 65536 ints
    float* enorm = (float*)((char*)d_ws + 65536 * sizeof(int));   // 512 floats

    vq_enorm<<<dim3(K_CODES), dim3(64), 0, stream>>>(cb, enorm);
    vq_argmin<<<dim3(1024), dim3(512), 0, stream>>>(z, cb, enorm, idx);
    vq_gather<<<dim3(1024), dim3(256), 0, stream>>>(cb, idx, out);
}

// Round 3
// 316.429 us; speedup vs baseline: 1.1178x; 1.1178x over previous
//
#include <hip/hip_runtime.h>
#include <hip/hip_bf16.h>

#define K_CODES 512
#define CDIM    256
#define HW      1024
#define NBATCH  64
#define SZ      260   // fallback kernel LDS stride

typedef float  f32x16 __attribute__((ext_vector_type(16)));
typedef short  bf16x8 __attribute__((ext_vector_type(8)));

__device__ __forceinline__ unsigned short f2bf(float x) {
    unsigned u = __float_as_uint(x);
    unsigned r = (u + 0x7FFFu + ((u >> 16) & 1u)) >> 16;   // RNE
    return (unsigned short)r;
}

// ---------------- Prep: en[512] fp32 + codebook bf16 ----------------
__global__ __launch_bounds__(64) void vq_prep(const float* __restrict__ cb,
                                              float* __restrict__ enorm,
                                              unsigned short* __restrict__ cb16) {
    int k = blockIdx.x;
    int l = threadIdx.x;
    float4 v = *reinterpret_cast<const float4*>(cb + (size_t)k * CDIM + l * 4);
    float s = (v.x * v.x + v.y * v.y) + (v.z * v.z + v.w * v.w);
#pragma unroll
    for (int off = 1; off < 64; off <<= 1) s += __shfl_xor(s, off, 64);
    if (l == 0) enorm[k] = s;
    ushort4 o;
    o.x = f2bf(v.x); o.y = f2bf(v.y); o.z = f2bf(v.z); o.w = f2bf(v.w);
    *reinterpret_cast<ushort4*>(cb16 + (size_t)k * CDIM + l * 4) = o;
}

// enorm-only prep for fallback path
__global__ __launch_bounds__(64) void vq_enorm(const float* __restrict__ cb,
                                               float* __restrict__ enorm) {
    int k = blockIdx.x;
    int l = threadIdx.x;
    float4 v = *reinterpret_cast<const float4*>(cb + (size_t)k * CDIM + l * 4);
    float s = (v.x * v.x + v.y * v.y) + (v.z * v.z + v.w * v.w);
#pragma unroll
    for (int off = 1; off < 64; off <<= 1) s += __shfl_xor(s, off, 64);
    if (l == 0) enorm[k] = s;
}

// ---------------- Pass 1: bf16 MFMA band maxima of dot(z, e) ----------------
// Block: 512 thr (8 waves), 256 z-rows. Wave w: rows w*32..w*32+31, all 512 codes.
// A = codes (from LDS es), B = z (regs, from LDS zs). C: col=lane&31 (z-row),
// row=(reg&3)+8*(reg>>2)+4*(lane>>5) (code). Band r = codes [32r, 32r+32).
// LDS layout: per row 256 bf16, 16B-unit swizzle u' = u ^ ((row>>2)&7).
__global__ __launch_bounds__(512) void vq_pass1(const float* __restrict__ z,
                                                const unsigned short* __restrict__ cb16,
                                                float* __restrict__ bm_out) {
    __shared__ __align__(16) unsigned short zs[256 * 256];
    __shared__ __align__(16) unsigned short es[32 * 256];

    const int t = threadIdx.x;
    const int l = t & 63, w = t >> 6;
    const int r0 = blockIdx.x << 8;
    const int b  = r0 >> 10, n0 = r0 & 1023;
    const float* zb = z + (size_t)b * (CDIM * HW);

    // ---- stage z: transpose + bf16, swizzled; write conflict analysis: banks
    // = (4*((c2>>2)^(l&7)) + (c2&3)) % 32 -> 8 groups x 8 lanes (b32, ~3x ok)
    unsigned* zsw = (unsigned*)zs;
#pragma unroll
    for (int p = 0; p < 16; ++p) {
        int c2 = (p << 3) + w;          // k-pair (dword) index 0..127
        int iq = l;                     // row-quad 0..63
        const float* g0 = zb + (size_t)(2 * c2) * HW + n0 + (iq << 2);
        float4 a  = *reinterpret_cast<const float4*>(g0);
        float4 bb = *reinterpret_cast<const float4*>(g0 + HW);
        int up = (((c2 >> 2) ^ (iq & 7)) << 2) + (c2 & 3);
        const float* ap = &a.x; const float* bp = &bb.x;
#pragma unroll
        for (int j = 0; j < 4; ++j) {
            unsigned pk = (unsigned)f2bf(ap[j]) | ((unsigned)f2bf(bp[j]) << 16);
            zsw[((iq << 2) + j) * 128 + up] = pk;
        }
    }
    __syncthreads();

    // ---- B-frags (z) into registers: 16 K-steps x 4 VGPR
    const int lrow = l & 31, lh = l >> 5;
    const int lf = (lrow >> 2) & 7;
    const int row = (w << 5) + lrow;
    bf16x8 zf[16];
#pragma unroll
    for (int s = 0; s < 16; ++s) {
        int u = (2 * s + lh) ^ lf;
        zf[s] = *reinterpret_cast<const bf16x8*>(&zs[row * 256 + (u << 3)]);
    }

    float bm[16];
#pragma unroll
    for (int r = 0; r < 16; ++r) bm[r] = -3.4e38f;

    for (int r = 0; r < 16; ++r) {
        __syncthreads();   // protect es from previous round's readers
        // stage code tile: 32 codes x 256 bf16 (1024 16B units, 2 per thread)
#pragma unroll
        for (int q = 0; q < 2; ++q) {
            int lin  = (q << 9) + t;
            int code = lin >> 5, u = lin & 31;
            uint4 v = *reinterpret_cast<const uint4*>(&cb16[(size_t)((r << 5) + code) * 256 + (u << 3)]);
            *reinterpret_cast<uint4*>(&es[code * 256 + ((u ^ ((code >> 2) & 7)) << 3)]) = v;
        }
        __syncthreads();

        f32x16 accA = {0.f,0.f,0.f,0.f,0.f,0.f,0.f,0.f,0.f,0.f,0.f,0.f,0.f,0.f,0.f,0.f};
        f32x16 accB = accA;
#pragma unroll
        for (int s = 0; s < 16; s += 2) {
            int uA = (2 * s + lh) ^ lf;
            int uB = (2 * s + 2 + lh) ^ lf;
            bf16x8 a0 = *reinterpret_cast<const bf16x8*>(&es[lrow * 256 + (uA << 3)]);
            bf16x8 a1 = *reinterpret_cast<const bf16x8*>(&es[lrow * 256 + (uB << 3)]);
            accA = __builtin_amdgcn_mfma_f32_32x32x16_bf16(a0, zf[s],     accA, 0, 0, 0);
            accB = __builtin_amdgcn_mfma_f32_32x32x16_bf16(a1, zf[s + 1], accB, 0, 0, 0);
        }
        float m = -3.4e38f;
#pragma unroll
        for (int i = 0; i < 16; ++i) m = fmaxf(m, accA[i] + accB[i]);
        bm[r] = m;
    }

    // merge lane pairs (l, l^32) -> full 32-code band max per z-row, write
#pragma unroll
    for (int r = 0; r < 16; ++r) bm[r] = fmaxf(bm[r], __shfl_xor(bm[r], 32, 64));
    if (lh == 0) {
        size_t grow = (size_t)(r0 + (w << 5) + lrow);
#pragma unroll
        for (int q = 0; q < 4; ++q) {
            float4 v = make_float4(bm[4*q], bm[4*q+1], bm[4*q+2], bm[4*q+3]);
            *reinterpret_cast<float4*>(&bm_out[grow * 16 + 4 * q]) = v;
        }
    }
}

// ---------------- Pass 2: flag bands by rigorous margin, exact fp32 rescore ----------------
__global__ __launch_bounds__(256) void vq_rescore(const float* __restrict__ z,
                                                  const float* __restrict__ cb,
                                                  const float* __restrict__ enb,
                                                  const float* __restrict__ bm_in,
                                                  int* __restrict__ idx_out) {
    __shared__ __align__(16) float zst[64 * 256];    // swizzled rows
    __shared__ __align__(16) float esr[64 * 268];    // 2 bands of 32 codes
    __shared__ float znl[64];
    __shared__ unsigned long long rowbest[64];
    __shared__ unsigned short lists[8][130];
    __shared__ int cnts[8];

    const int t  = threadIdx.x;
    const int r0 = blockIdx.x << 6;
    const int b  = r0 >> 10, n0 = r0 & 1023;
    const float* zb = z + (size_t)b * (CDIM * HW);

    if (t < 8)  cnts[t] = 0;
    if (t < 64) rowbest[t] = 0xFFFFFFFFFFFFFFFFull;

    // stage z transposed fp32, swizzled (banks fully spread: all 32)
#pragma unroll
    for (int p = 0; p < 16; ++p) {
        int c  = (p << 4) + (t >> 4);
        int i0 = (t & 15) << 2;
        float4 v = *reinterpret_cast<const float4*>(zb + (size_t)c * HW + n0 + i0);
        int u = c >> 2, c3 = c & 3;
        const float* vp = &v.x;
#pragma unroll
        for (int j = 0; j < 4; ++j) {
            int rw = i0 + j;
            zst[rw * 256 + ((u ^ ((rw >> 2) & 7)) << 2) + c3] = vp[j];
        }
    }
    __syncthreads();

    if (t < 64) {
        // zn exactly as the validated fallback kernel; sabs for the margin
        float s0 = 0.f, s1 = 0.f, s2 = 0.f, s3 = 0.f, sa = 0.f;
        int f = (t >> 2) & 7;
        for (int u = 0; u < 64; ++u) {
            float4 v = *reinterpret_cast<const float4*>(&zst[t * 256 + ((u ^ f) << 2)]);
            s0 += v.x * v.x; s1 += v.y * v.y; s2 += v.z * v.z; s3 += v.w * v.w;
            sa += fabsf(v.x) + fabsf(v.y) + fabsf(v.z) + fabsf(v.w);
        }
        znl[t] = (s0 + s1) + (s2 + s3);

        const float* bmr = bm_in + (size_t)(r0 + t) * 16;
        float bmv[16]; float g = -3.4e38f;
#pragma unroll
        for (int r = 0; r < 16; ++r) { bmv[r] = bmr[r]; g = fmaxf(g, bmv[r]); }
        // |dot_bf - dot| <= sabs*(1/512)*2^-8*(1+eps); + en omission 256/512^2/2
        // + d-quantization 3.05e-5 (dot units) + safety
        float thr = g - (sa * 1.6e-5f + 6.0e-4f);
#pragma unroll
        for (int r = 0; r < 16; ++r) {
            if (bmv[r] >= thr) {
                int rr = r >> 1, side = r & 1;
                int pos = atomicAdd(&cnts[rr], 1);
                lists[rr][pos] = (unsigned short)((t << 1) | side);
            }
        }
    }
    __syncthreads();

    for (int rr = 0; rr < 8; ++rr) {
        int ne = cnts[rr];                     // uniform across block
        if (ne > 0) {
            // stage 64 code rows fp32, coalesced
#pragma unroll
            for (int q = 0; q < 16; ++q) {
                int unit = (q << 8) + t;
                int cr = unit >> 6, k4 = (unit & 63) << 2;
                *reinterpret_cast<float4*>(&esr[cr * 268 + k4]) =
                    *reinterpret_cast<const float4*>(&cb[(size_t)((rr << 6) + cr) * CDIM + k4]);
            }
            __syncthreads();
            int slot = t >> 5, lane = t & 31;
            for (int e = slot; e < ne; e += 8) {
                int ent  = lists[rr][e];
                int rw   = ent >> 1, side = ent & 1;
                int cr   = (side << 5) + lane;
                int gcode = (rr << 6) + cr;
                const float* ep = &esr[cr * 268];
                const float* zp = &zst[rw * 256];
                int f = (rw >> 2) & 7;
                float acc = 0.f;
                for (int u = 0; u < 64; ++u) {
                    float4 zv = *reinterpret_cast<const float4*>(&zp[(u ^ f) << 2]);
                    float4 ev = *reinterpret_cast<const float4*>(&ep[u << 2]);
                    acc += zv.x * ev.x;   // sequential fp32 FMA chain
                    acc += zv.y * ev.y;   // (identical form to validated kernel)
                    acc += zv.z * ev.z;
                    acc += zv.w * ev.w;
                }
                float d = (znl[rw] - 2.0f * acc) + enb[gcode];
                unsigned long long pk =
                    (((unsigned long long)__float_as_uint(d)) << 32) | (unsigned)gcode;
#pragma unroll
                for (int o = 1; o < 32; o <<= 1) {
                    unsigned long long q2 = __shfl_xor(pk, o, 64);
                    pk = (q2 < pk) ? q2 : pk;
                }
                if (lane == 0) atomicMin(&rowbest[rw], pk);
            }
            __syncthreads();
        }
    }
    __syncthreads();
    if (t < 64) idx_out[r0 + t] = (int)(unsigned)(rowbest[t] & 0xFFFFFFFFu);
}

// ---------------- Fallback exact argmin (validated round-2 kernel) ----------------
__global__ __launch_bounds__(512) void vq_argmin(const float* __restrict__ z,
                                                 const float* __restrict__ cb,
                                                 const float* __restrict__ enorm,
                                                 int* __restrict__ out_idx) {
    __shared__ float zs[64][SZ];
    __shared__ float es[64][SZ];
    __shared__ float ens[K_CODES];
    __shared__ float zn[64];
    __shared__ float red_d[64][32];
    __shared__ int   red_i[64][32];

    const int t  = threadIdx.x;
    const int r0 = blockIdx.x * 64;
    const int b  = r0 >> 10;
    const int n0 = r0 & 1023;
    const float* zb = z + (size_t)b * CDIM * HW;

#pragma unroll
    for (int p = 0; p < 8; ++p) {
        int lin = p * 512 + t;
        int c   = lin >> 4;
        int i0  = (lin & 15) << 2;
        float4 v = *reinterpret_cast<const float4*>(zb + (size_t)c * HW + n0 + i0);
        zs[i0 + 0][c] = v.x; zs[i0 + 1][c] = v.y;
        zs[i0 + 2][c] = v.z; zs[i0 + 3][c] = v.w;
    }
    if (t < K_CODES) ens[t] = enorm[t];
    __syncthreads();

    if (t < 64) {
        float s0 = 0.f, s1 = 0.f, s2 = 0.f, s3 = 0.f;
        for (int c = 0; c < CDIM; c += 4) {
            float4 v = *reinterpret_cast<const float4*>(&zs[t][c]);
            s0 += v.x * v.x; s1 += v.y * v.y; s2 += v.z * v.z; s3 += v.w * v.w;
        }
        zn[t] = (s0 + s1) + (s2 + s3);
    }

    const int ty = t >> 5, tx = t & 31, row0 = ty * 4;
    float best_d[4]; int best_i[4];
#pragma unroll
    for (int i = 0; i < 4; ++i) { best_d[i] = 3.4e38f; best_i[i] = 0; }

    for (int K0 = 0; K0 < K_CODES; K0 += 64) {
        __syncthreads();
#pragma unroll
        for (int p = 0; p < 8; ++p) {
            int lin = p * 512 + t;
            int j = lin >> 6, c4 = (lin & 63) << 2;
            *reinterpret_cast<float4*>(&es[j][c4]) =
                *reinterpret_cast<const float4*>(cb + (size_t)(K0 + j) * CDIM + c4);
        }
        __syncthreads();

        float acc[4][2];
#pragma unroll
        for (int i = 0; i < 4; ++i) { acc[i][0] = 0.f; acc[i][1] = 0.f; }
#pragma unroll 4
        for (int k = 0; k < CDIM; k += 4) {
            float4 a0 = *reinterpret_cast<const float4*>(&zs[row0 + 0][k]);
            float4 a1 = *reinterpret_cast<const float4*>(&zs[row0 + 1][k]);
            float4 a2 = *reinterpret_cast<const float4*>(&zs[row0 + 2][k]);
            float4 a3 = *reinterpret_cast<const float4*>(&zs[row0 + 3][k]);
            float4 e0 = *reinterpret_cast<const float4*>(&es[tx][k]);
            float4 e1 = *reinterpret_cast<const float4*>(&es[tx + 32][k]);
            float4 aa[4] = {a0, a1, a2, a3};
#pragma unroll
            for (int i = 0; i < 4; ++i) {
#pragma unroll
                for (int j = 0; j < 2; ++j) {
                    float4 e = j ? e1 : e0;
                    acc[i][j] += aa[i].x * e.x; acc[i][j] += aa[i].y * e.y;
                    acc[i][j] += aa[i].z * e.z; acc[i][j] += aa[i].w * e.w;
                }
            }
        }
#pragma unroll
        for (int i = 0; i < 4; ++i) {
            float zni = zn[row0 + i];
#pragma unroll
            for (int j = 0; j < 2; ++j) {
                int code = K0 + j * 32 + tx;
                float d = (zni - 2.0f * acc[i][j]) + ens[code];
                if (d < best_d[i]) { best_d[i] = d; best_i[i] = code; }
            }
        }
    }
    __syncthreads();
#pragma unroll
    for (int i = 0; i < 4; ++i) {
        red_d[row0 + i][tx] = best_d[i];
        red_i[row0 + i][tx] = best_i[i];
    }
    __syncthreads();
    if (t < 64) {
        float bd = red_d[t][0]; int bi = red_i[t][0];
        for (int x = 1; x < 32; ++x) {
            float d = red_d[t][x]; int ii = red_i[t][x];
            if (d < bd || (d == bd && ii < bi)) { bd = d; bi = ii; }
        }
        out_idx[r0 + t] = bi;
    }
}

// ---------------- Gather + transpose write + index write ----------------
__global__ __launch_bounds__(256) void vq_gather(const float* __restrict__ cb,
                                                 const int* __restrict__ idx,
                                                 float* __restrict__ out) {
    const int blk = blockIdx.x;
    const int b   = blk >> 4;
    const int n0  = (blk & 15) << 6;
    const int t   = threadIdx.x;
    const int n   = t & 63;
    const int c0  = t >> 6;
    const int code = idx[b * HW + n0 + n];
    const float* crow = cb + (size_t)code * CDIM;
    float* ob = out + (size_t)b * CDIM * HW + n0 + n;

    if (c0 == 0)
        out[(size_t)NBATCH * CDIM * HW + (size_t)b * HW + n0 + n] = (float)code;

#pragma unroll 4
    for (int q = 0; q < 64; q += 4) {
        int c = c0 * 64 + q;
        float4 v = *reinterpret_cast<const float4*>(crow + c);
        ob[(size_t)(c + 0) * HW] = v.x;
        ob[(size_t)(c + 1) * HW] = v.y;
        ob[(size_t)(c + 2) * HW] = v.z;
        ob[(size_t)(c + 3) * HW] = v.w;
    }
}

extern "C" void kernel_launch(void* const* d_in, const int* in_sizes, int n_in,
                              void* d_out, int out_size, void* d_ws, size_t ws_size,
                              hipStream_t stream) {
    const float* z  = (const float*)d_in[0];
    const float* cb = (const float*)d_in[1];
    float* out = (float*)d_out;

    // ws layout
    int*            idx  = (int*)d_ws;                                  // 262144 B
    float*          en   = (float*)((char*)d_ws + 262144);              // 2048 B
    unsigned short* cb16 = (unsigned short*)((char*)d_ws + 264192);     // 262144 B
    float*          bm   = (float*)((char*)d_ws + 526336);              // 4194304 B
    const size_t NEED_FULL = 4720640;

    if (ws_size >= NEED_FULL) {
        vq_prep   <<<dim3(K_CODES), dim3(64),  0, stream>>>(cb, en, cb16);
        vq_pass1  <<<dim3(256),     dim3(512), 0, stream>>>(z, cb16, bm);
        vq_rescore<<<dim3(1024),    dim3(256), 0, stream>>>(z, cb, en, bm, idx);
    } else {
        vq_enorm  <<<dim3(K_CODES), dim3(64),  0, stream>>>(cb, en);
        vq_argmin <<<dim3(1024),    dim3(512), 0, stream>>>(z, cb, en, idx);
    }
    vq_gather<<<dim3(1024), dim3(256), 0, stream>>>(cb, idx, out);
}

// Round 4
// 126.628 us; speedup vs baseline: 2.7934x; 2.4989x over previous
//
#include <hip/hip_runtime.h>
#include <hip/hip_bf16.h>

#define K_CODES 512
#define CDIM    256
#define HW      1024
#define NBATCH  64
#define SZ      260   // fallback kernel LDS stride

typedef float  f32x16 __attribute__((ext_vector_type(16)));
typedef short  bf16x8 __attribute__((ext_vector_type(8)));

__device__ __forceinline__ unsigned short f2bf(float x) {
    unsigned u = __float_as_uint(x);
    unsigned r = (u + 0x7FFFu + ((u >> 16) & 1u)) >> 16;   // RNE
    return (unsigned short)r;
}

// ---------------- Prep: en[512] fp32 + codebook bf16 ----------------
__global__ __launch_bounds__(64) void vq_prep(const float* __restrict__ cb,
                                              float* __restrict__ enorm,
                                              unsigned short* __restrict__ cb16) {
    int k = blockIdx.x;
    int l = threadIdx.x;
    float4 v = *reinterpret_cast<const float4*>(cb + (size_t)k * CDIM + l * 4);
    float s = (v.x * v.x + v.y * v.y) + (v.z * v.z + v.w * v.w);
#pragma unroll
    for (int off = 1; off < 64; off <<= 1) s += __shfl_xor(s, off, 64);
    if (l == 0) enorm[k] = s;
    ushort4 o;
    o.x = f2bf(v.x); o.y = f2bf(v.y); o.z = f2bf(v.z); o.w = f2bf(v.w);
    *reinterpret_cast<ushort4*>(cb16 + (size_t)k * CDIM + l * 4) = o;
}

__global__ __launch_bounds__(64) void vq_enorm(const float* __restrict__ cb,
                                               float* __restrict__ enorm) {
    int k = blockIdx.x;
    int l = threadIdx.x;
    float4 v = *reinterpret_cast<const float4*>(cb + (size_t)k * CDIM + l * 4);
    float s = (v.x * v.x + v.y * v.y) + (v.z * v.z + v.w * v.w);
#pragma unroll
    for (int off = 1; off < 64; off <<= 1) s += __shfl_xor(s, off, 64);
    if (l == 0) enorm[k] = s;
}

// ---------------- Pass 1: MFMA sweep A (max) + sweep B (per-code candidate emission) ----------------
// 256 z-rows/block, 512 thr (8 waves). A=codes (LDS), B=z (regs).
// C layout (m74/m101): col=lane&31 (z-row), row=(i&3)+8*(i>>2)+4*(lane>>5) (code in band).
__global__ __launch_bounds__(512) void vq_pass1(const float* __restrict__ z,
                                                const unsigned short* __restrict__ cb16,
                                                unsigned* __restrict__ cnt_out,
                                                unsigned short* __restrict__ codes_out,
                                                int* __restrict__ idx_out) {
    __shared__ __align__(16) unsigned short zs[256 * 256];
    __shared__ __align__(16) unsigned short es[32 * 256];
    __shared__ unsigned       cnt_lds[256];
    __shared__ __align__(16) unsigned short codes_lds[256 * 16];

    const int t = threadIdx.x;
    const int l = t & 63, w = t >> 6;
    const int r0 = blockIdx.x << 8;
    const int b  = r0 >> 10, n0 = r0 & 1023;
    const float* zb = z + (size_t)b * (CDIM * HW);

    if (t < 256) cnt_lds[t] = 0;

    // stage z: transpose + bf16, 16B-unit swizzle u' = u ^ ((row>>2)&7)
    unsigned* zsw = (unsigned*)zs;
#pragma unroll
    for (int p = 0; p < 16; ++p) {
        int c2 = (p << 3) + w;
        int iq = l;
        const float* g0 = zb + (size_t)(2 * c2) * HW + n0 + (iq << 2);
        float4 a  = *reinterpret_cast<const float4*>(g0);
        float4 bb = *reinterpret_cast<const float4*>(g0 + HW);
        int up = (((c2 >> 2) ^ (iq & 7)) << 2) + (c2 & 3);
        const float* ap = &a.x; const float* bp = &bb.x;
#pragma unroll
        for (int j = 0; j < 4; ++j) {
            unsigned pk = (unsigned)f2bf(ap[j]) | ((unsigned)f2bf(bp[j]) << 16);
            zsw[((iq << 2) + j) * 128 + up] = pk;
        }
    }
    __syncthreads();

    const int lrow = l & 31, lh = l >> 5;
    const int lf = (lrow >> 2) & 7;
    const int row = (w << 5) + lrow;
    bf16x8 zf[16];
#pragma unroll
    for (int s = 0; s < 16; ++s) {
        int u = (2 * s + lh) ^ lf;
        zf[s] = *reinterpret_cast<const bf16x8*>(&zs[row * 256 + (u << 3)]);
    }

    // sa = sum|z_bf| for this row (lane holds half the k's; add lane^32 part)
    float sa = 0.f;
#pragma unroll
    for (int s = 0; s < 16; ++s)
#pragma unroll
        for (int j = 0; j < 8; ++j)
            sa += fabsf(__uint_as_float(((unsigned)(unsigned short)zf[s][j]) << 16));
    sa += __shfl_xor(sa, 32, 64);

    // ---- Sweep A: running max of dot_bf over all 512 codes
    float g_lane = -3.4e38f;
    for (int r = 0; r < 16; ++r) {
        __syncthreads();
#pragma unroll
        for (int q = 0; q < 2; ++q) {
            int lin  = (q << 9) + t;
            int code = lin >> 5, u = lin & 31;
            uint4 v = *reinterpret_cast<const uint4*>(&cb16[(size_t)((r << 5) + code) * 256 + (u << 3)]);
            *reinterpret_cast<uint4*>(&es[code * 256 + ((u ^ ((code >> 2) & 7)) << 3)]) = v;
        }
        __syncthreads();

        f32x16 accA = {0.f,0.f,0.f,0.f,0.f,0.f,0.f,0.f,0.f,0.f,0.f,0.f,0.f,0.f,0.f,0.f};
        f32x16 accB = accA;
#pragma unroll
        for (int s = 0; s < 16; s += 2) {
            int uA = (2 * s + lh) ^ lf;
            int uB = (2 * s + 2 + lh) ^ lf;
            bf16x8 a0 = *reinterpret_cast<const bf16x8*>(&es[lrow * 256 + (uA << 3)]);
            bf16x8 a1 = *reinterpret_cast<const bf16x8*>(&es[lrow * 256 + (uB << 3)]);
            accA = __builtin_amdgcn_mfma_f32_32x32x16_bf16(a0, zf[s],     accA, 0, 0, 0);
            accB = __builtin_amdgcn_mfma_f32_32x32x16_bf16(a1, zf[s + 1], accB, 0, 0, 0);
        }
#pragma unroll
        for (int i = 0; i < 16; ++i) g_lane = fmaxf(g_lane, accA[i] + accB[i]);
    }
    float g = fmaxf(g_lane, __shfl_xor(g_lane, 32, 64));
    const float thr = g - (sa * 1.7e-5f + 6.0e-4f);

    // ---- Sweep B: recompute (bit-identical) and emit codes >= thr
    for (int r = 0; r < 16; ++r) {
        __syncthreads();
#pragma unroll
        for (int q = 0; q < 2; ++q) {
            int lin  = (q << 9) + t;
            int code = lin >> 5, u = lin & 31;
            uint4 v = *reinterpret_cast<const uint4*>(&cb16[(size_t)((r << 5) + code) * 256 + (u << 3)]);
            *reinterpret_cast<uint4*>(&es[code * 256 + ((u ^ ((code >> 2) & 7)) << 3)]) = v;
        }
        __syncthreads();

        f32x16 accA = {0.f,0.f,0.f,0.f,0.f,0.f,0.f,0.f,0.f,0.f,0.f,0.f,0.f,0.f,0.f,0.f};
        f32x16 accB = accA;
#pragma unroll
        for (int s = 0; s < 16; s += 2) {
            int uA = (2 * s + lh) ^ lf;
            int uB = (2 * s + 2 + lh) ^ lf;
            bf16x8 a0 = *reinterpret_cast<const bf16x8*>(&es[lrow * 256 + (uA << 3)]);
            bf16x8 a1 = *reinterpret_cast<const bf16x8*>(&es[lrow * 256 + (uB << 3)]);
            accA = __builtin_amdgcn_mfma_f32_32x32x16_bf16(a0, zf[s],     accA, 0, 0, 0);
            accB = __builtin_amdgcn_mfma_f32_32x32x16_bf16(a1, zf[s + 1], accB, 0, 0, 0);
        }
#pragma unroll
        for (int i = 0; i < 16; ++i) {
            float v = accA[i] + accB[i];
            if (v >= thr) {
                int code = (r << 5) + (i & 3) + 8 * (i >> 2) + 4 * lh;
                unsigned pos = atomicAdd(&cnt_lds[row], 1u);
                if (pos < 16) codes_lds[row * 16 + pos] = (unsigned short)code;
            }
        }
    }
    __syncthreads();

    if (t < 256) {
        unsigned c = cnt_lds[t];
        cnt_out[r0 + t] = c;
        if (c == 1) idx_out[r0 + t] = (int)codes_lds[t * 16];
        uint4* src = reinterpret_cast<uint4*>(&codes_lds[t * 16]);
        uint4* dst = reinterpret_cast<uint4*>(&codes_out[(size_t)(r0 + t) * 16]);
        dst[0] = src[0]; dst[1] = src[1];
    }
}

// ---------------- Pass 2: exact fp32 rescore of multi-candidate rows ----------------
// 32 rows/block, 256 thr, ~33KB LDS -> ~4 blocks/CU. 16-lane slot per row.
__global__ __launch_bounds__(256) void vq_rescore(const float* __restrict__ z,
                                                  const float* __restrict__ cb,
                                                  const float* __restrict__ enb,
                                                  const unsigned* __restrict__ cnt_in,
                                                  const unsigned short* __restrict__ codes_in,
                                                  int* __restrict__ idx_out) {
    __shared__ __align__(16) float zst[32 * 256];
    __shared__ float znl[32];
    __shared__ unsigned cntl[32];
    __shared__ unsigned short rows2[32];
    __shared__ int nr2;

    const int t  = threadIdx.x;
    const int r0 = blockIdx.x << 5;
    const int b  = r0 >> 10, n0 = r0 & 1023;
    const float* zb = z + (size_t)b * (CDIM * HW);

    // stage z fp32 transposed, swizzled (identical formula to validated kernel)
#pragma unroll
    for (int p = 0; p < 8; ++p) {
        int c  = (p << 5) + (t >> 3);
        int i0 = (t & 7) << 2;
        float4 v = *reinterpret_cast<const float4*>(zb + (size_t)c * HW + n0 + i0);
        int u = c >> 2, c3 = c & 3;
        const float* vp = &v.x;
#pragma unroll
        for (int j = 0; j < 4; ++j) {
            int rw = i0 + j;
            zst[rw * 256 + ((u ^ ((rw >> 2) & 7)) << 2) + c3] = vp[j];
        }
    }
    if (t == 0) nr2 = 0;
    __syncthreads();

    if (t < 32) {
        float s0 = 0.f, s1 = 0.f, s2 = 0.f, s3 = 0.f;
        int f = (t >> 2) & 7;
        for (int u = 0; u < 64; ++u) {
            float4 v = *reinterpret_cast<const float4*>(&zst[t * 256 + ((u ^ f) << 2)]);
            s0 += v.x * v.x; s1 += v.y * v.y; s2 += v.z * v.z; s3 += v.w * v.w;
        }
        znl[t] = (s0 + s1) + (s2 + s3);
        unsigned c = cnt_in[r0 + t];
        cntl[t] = c;
        if (c != 1u) {
            int p = atomicAdd(&nr2, 1);
            rows2[p] = (unsigned short)t;
        }
    }
    __syncthreads();

    const int w = t >> 6, lane = t & 63;
    const int slot = lane >> 4, j = lane & 15;
    const int n2 = nr2;

    for (int base = w * 4; base < n2; base += 16) {
        int ri = base + slot;
        bool active = (ri < n2);
        int row_l = active ? (int)rows2[ri] : 0;
        unsigned cr = cntl[row_l];
        const float* zp = &zst[row_l * 256];
        const int f = (row_l >> 2) & 7;
        const float zn = znl[row_l];
        unsigned long long pk = 0xFFFFFFFFFFFFFFFFull;

        if (cr <= 16u) {
            if (active && j < (int)cr) {
                int code = (int)codes_in[(size_t)(r0 + row_l) * 16 + j];
                const float* ep = cb + (size_t)code * CDIM;
                float acc = 0.f;
                for (int u = 0; u < 64; ++u) {
                    float4 zv = *reinterpret_cast<const float4*>(&zp[(u ^ f) << 2]);
                    float4 ev = *reinterpret_cast<const float4*>(ep + (u << 2));
                    acc += zv.x * ev.x;   // sequential fp32 FMA chain
                    acc += zv.y * ev.y;   // (identical order to validated kernel)
                    acc += zv.z * ev.z;
                    acc += zv.w * ev.w;
                }
                float d = (zn - 2.0f * acc) + enb[code];
                pk = (((unsigned long long)__float_as_uint(d)) << 32) | (unsigned)code;
            }
        } else if (active) {
            // overflow (cnt>16): full 512-code exact scan (essentially never taken)
            for (int b2 = 0; b2 < 32; ++b2) {
                int code = (b2 << 4) + j;
                const float* ep = cb + (size_t)code * CDIM;
                float acc = 0.f;
                for (int u = 0; u < 64; ++u) {
                    float4 zv = *reinterpret_cast<const float4*>(&zp[(u ^ f) << 2]);
                    float4 ev = *reinterpret_cast<const float4*>(ep + (u << 2));
                    acc += zv.x * ev.x; acc += zv.y * ev.y;
                    acc += zv.z * ev.z; acc += zv.w * ev.w;
                }
                float d = (zn - 2.0f * acc) + enb[code];
                unsigned long long q2 =
                    (((unsigned long long)__float_as_uint(d)) << 32) | (unsigned)code;
                if (q2 < pk) pk = q2;
            }
        }
        // min-reduce within the 16-lane slot
#pragma unroll
        for (int o = 1; o < 16; o <<= 1) {
            unsigned long long q2 = __shfl_xor(pk, o, 64);
            if (q2 < pk) pk = q2;
        }
        if (active && j == 0)
            idx_out[r0 + row_l] = (int)(unsigned)(pk & 0xFFFFFFFFu);
    }
}

// ---------------- Fallback exact argmin (validated round-2 kernel) ----------------
__global__ __launch_bounds__(512) void vq_argmin(const float* __restrict__ z,
                                                 const float* __restrict__ cb,
                                                 const float* __restrict__ enorm,
                                                 int* __restrict__ out_idx) {
    __shared__ float zs[64][SZ];
    __shared__ float es[64][SZ];
    __shared__ float ens[K_CODES];
    __shared__ float zn[64];
    __shared__ float red_d[64][32];
    __shared__ int   red_i[64][32];

    const int t  = threadIdx.x;
    const int r0 = blockIdx.x * 64;
    const int b  = r0 >> 10;
    const int n0 = r0 & 1023;
    const float* zb = z + (size_t)b * CDIM * HW;

#pragma unroll
    for (int p = 0; p < 8; ++p) {
        int lin = p * 512 + t;
        int c   = lin >> 4;
        int i0  = (lin & 15) << 2;
        float4 v = *reinterpret_cast<const float4*>(zb + (size_t)c * HW + n0 + i0);
        zs[i0 + 0][c] = v.x; zs[i0 + 1][c] = v.y;
        zs[i0 + 2][c] = v.z; zs[i0 + 3][c] = v.w;
    }
    if (t < K_CODES) ens[t] = enorm[t];
    __syncthreads();

    if (t < 64) {
        float s0 = 0.f, s1 = 0.f, s2 = 0.f, s3 = 0.f;
        for (int c = 0; c < CDIM; c += 4) {
            float4 v = *reinterpret_cast<const float4*>(&zs[t][c]);
            s0 += v.x * v.x; s1 += v.y * v.y; s2 += v.z * v.z; s3 += v.w * v.w;
        }
        zn[t] = (s0 + s1) + (s2 + s3);
    }

    const int ty = t >> 5, tx = t & 31, row0 = ty * 4;
    float best_d[4]; int best_i[4];
#pragma unroll
    for (int i = 0; i < 4; ++i) { best_d[i] = 3.4e38f; best_i[i] = 0; }

    for (int K0 = 0; K0 < K_CODES; K0 += 64) {
        __syncthreads();
#pragma unroll
        for (int p = 0; p < 8; ++p) {
            int lin = p * 512 + t;
            int j = lin >> 6, c4 = (lin & 63) << 2;
            *reinterpret_cast<float4*>(&es[j][c4]) =
                *reinterpret_cast<const float4*>(cb + (size_t)(K0 + j) * CDIM + c4);
        }
        __syncthreads();

        float acc[4][2];
#pragma unroll
        for (int i = 0; i < 4; ++i) { acc[i][0] = 0.f; acc[i][1] = 0.f; }
#pragma unroll 4
        for (int k = 0; k < CDIM; k += 4) {
            float4 a0 = *reinterpret_cast<const float4*>(&zs[row0 + 0][k]);
            float4 a1 = *reinterpret_cast<const float4*>(&zs[row0 + 1][k]);
            float4 a2 = *reinterpret_cast<const float4*>(&zs[row0 + 2][k]);
            float4 a3 = *reinterpret_cast<const float4*>(&zs[row0 + 3][k]);
            float4 e0 = *reinterpret_cast<const float4*>(&es[tx][k]);
            float4 e1 = *reinterpret_cast<const float4*>(&es[tx + 32][k]);
            float4 aa[4] = {a0, a1, a2, a3};
#pragma unroll
            for (int i = 0; i < 4; ++i) {
#pragma unroll
                for (int j = 0; j < 2; ++j) {
                    float4 e = j ? e1 : e0;
                    acc[i][j] += aa[i].x * e.x; acc[i][j] += aa[i].y * e.y;
                    acc[i][j] += aa[i].z * e.z; acc[i][j] += aa[i].w * e.w;
                }
            }
        }
#pragma unroll
        for (int i = 0; i < 4; ++i) {
            float zni = zn[row0 + i];
#pragma unroll
            for (int j = 0; j < 2; ++j) {
                int code = K0 + j * 32 + tx;
                float d = (zni - 2.0f * acc[i][j]) + ens[code];
                if (d < best_d[i]) { best_d[i] = d; best_i[i] = code; }
            }
        }
    }
    __syncthreads();
#pragma unroll
    for (int i = 0; i < 4; ++i) {
        red_d[row0 + i][tx] = best_d[i];
        red_i[row0 + i][tx] = best_i[i];
    }
    __syncthreads();
    if (t < 64) {
        float bd = red_d[t][0]; int bi = red_i[t][0];
        for (int x = 1; x < 32; ++x) {
            float d = red_d[t][x]; int ii = red_i[t][x];
            if (d < bd || (d == bd && ii < bi)) { bd = d; bi = ii; }
        }
        out_idx[r0 + t] = bi;
    }
}

// ---------------- Gather + transpose write + index write ----------------
__global__ __launch_bounds__(256) void vq_gather(const float* __restrict__ cb,
                                                 const int* __restrict__ idx,
                                                 float* __restrict__ out) {
    const int blk = blockIdx.x;
    const int b   = blk >> 4;
    const int n0  = (blk & 15) << 6;
    const int t   = threadIdx.x;
    const int n   = t & 63;
    const int c0  = t >> 6;
    const int code = idx[b * HW + n0 + n];
    const float* crow = cb + (size_t)code * CDIM;
    float* ob = out + (size_t)b * CDIM * HW + n0 + n;

    if (c0 == 0)
        out[(size_t)NBATCH * CDIM * HW + (size_t)b * HW + n0 + n] = (float)code;

#pragma unroll 4
    for (int q = 0; q < 64; q += 4) {
        int c = c0 * 64 + q;
        float4 v = *reinterpret_cast<const float4*>(crow + c);
        ob[(size_t)(c + 0) * HW] = v.x;
        ob[(size_t)(c + 1) * HW] = v.y;
        ob[(size_t)(c + 2) * HW] = v.z;
        ob[(size_t)(c + 3) * HW] = v.w;
    }
}

extern "C" void kernel_launch(void* const* d_in, const int* in_sizes, int n_in,
                              void* d_out, int out_size, void* d_ws, size_t ws_size,
                              hipStream_t stream) {
    const float* z  = (const float*)d_in[0];
    const float* cb = (const float*)d_in[1];
    float* out = (float*)d_out;

    // ws layout
    int*            idx   = (int*)d_ws;                                  // 262144 B
    float*          en    = (float*)((char*)d_ws + 262144);              // 2048 B
    unsigned short* cb16  = (unsigned short*)((char*)d_ws + 264192);     // 262144 B
    unsigned*       cnt   = (unsigned*)((char*)d_ws + 526336);           // 262144 B
    unsigned short* codes = (unsigned short*)((char*)d_ws + 788480);     // 2097152 B
    const size_t NEED_FULL = 2885632;

    if (ws_size >= NEED_FULL) {
        vq_prep   <<<dim3(K_CODES), dim3(64),  0, stream>>>(cb, en, cb16);
        vq_pass1  <<<dim3(256),     dim3(512), 0, stream>>>(z, cb16, cnt, codes, idx);
        vq_rescore<<<dim3(2048),    dim3(256), 0, stream>>>(z, cb, en, cnt, codes, idx);
    } else {
        vq_enorm  <<<dim3(K_CODES), dim3(64),  0, stream>>>(cb, en);
        vq_argmin <<<dim3(1024),    dim3(512), 0, stream>>>(z, cb, en, idx);
    }
    vq_gather<<<dim3(1024), dim3(256), 0, stream>>>(cb, idx, out);
}